// Round 1
// baseline (1740.610 us; speedup 1.0000x reference)
//
#include <hip/hip_runtime.h>
#include <hip/hip_bf16.h>

#define NB 8
#define CC 64
#define HH 256
#define WW 256
#define HWP 65536          // H*W
#define NC 512             // NB*CC

// ---------------- LN stats: one block per (n,c) plane --------------------
// Computes a = rstd*ln_w[c], b = ln_b[c] - mean*rstd*ln_w[c]
__global__ __launch_bounds__(256) void ln_stats_kernel(
    const float* __restrict__ x, const float* __restrict__ lw,
    const float* __restrict__ lb, float* __restrict__ a, float* __restrict__ b) {
  int plane = blockIdx.x;            // n*64 + c
  int c = plane & 63;
  const float4* p4 = (const float4*)(x + (size_t)plane * HWP);
  float s = 0.f, s2 = 0.f;
  for (int i = threadIdx.x; i < HWP / 4; i += 256) {
    float4 v = p4[i];
    s  += v.x + v.y + v.z + v.w;
    s2 += v.x * v.x + v.y * v.y + v.z * v.z + v.w * v.w;
  }
  for (int off = 32; off; off >>= 1) {
    s  += __shfl_down(s, off);
    s2 += __shfl_down(s2, off);
  }
  __shared__ float ls[4], ls2[4];
  int wid = threadIdx.x >> 6, lid = threadIdx.x & 63;
  if (lid == 0) { ls[wid] = s; ls2[wid] = s2; }
  __syncthreads();
  if (threadIdx.x == 0) {
    float S  = ls[0] + ls[1] + ls[2] + ls[3];
    float S2 = ls2[0] + ls2[1] + ls2[2] + ls2[3];
    float mean = S * (1.f / (float)HWP);
    float var  = S2 * (1.f / (float)HWP) - mean * mean;
    float rstd = rsqrtf(var + 1e-6f);
    float av = rstd * lw[c];
    a[plane] = av;
    b[plane] = lb[c] - mean * av;
  }
}

// -------- fold LN into pw weights: wf[n][o][i] = w[o][i]*a[n][i];
//          cf[n][o] = sum_i w[o][i]*b[n][i] + pb[o] -------------------------
__global__ void fold_kernel(const float* __restrict__ w, const float* __restrict__ pb,
                            const float* __restrict__ a, const float* __restrict__ b,
                            float* __restrict__ wf, float* __restrict__ cf, int O) {
  int idx = blockIdx.x * blockDim.x + threadIdx.x;   // n*O + o
  if (idx >= NB * O) return;
  int n = idx / O, o = idx - n * O;
  const float* an = a + n * 64;
  const float* bn = b + n * 64;
  const float* wo = w + o * 64;
  float* wfo = wf + (size_t)idx * 64;
  float cc = pb[o];
  for (int i = 0; i < 64; i++) { float wv = wo[i]; wfo[i] = wv * an[i]; cc += wv * bn[i]; }
  cf[idx] = cc;
}

// ---------------- pw1: z[n,o,p] = sum_i W'[n,o,i]*x[n,i,p] + c'[n,o], O=128, bf16 out
__global__ __launch_bounds__(256) void pw1_kernel(
    const float* __restrict__ x, const float* __restrict__ wf,
    const float* __restrict__ cf, __hip_bfloat16* __restrict__ z) {
  __shared__ float sw[128 * 64];
  __shared__ float sc[128];
  int n = blockIdx.y;
  const float* wfn = wf + (size_t)n * 128 * 64;
  for (int i = threadIdx.x; i < 128 * 64; i += 256) sw[i] = wfn[i];
  if (threadIdx.x < 128) sc[threadIdx.x] = cf[n * 128 + threadIdx.x];
  __syncthreads();
  int p = blockIdx.x * 256 + threadIdx.x;
  const float* xn = x + (size_t)n * CC * HWP + p;
  float v[64];
  #pragma unroll
  for (int i = 0; i < 64; i++) v[i] = xn[(size_t)i * HWP];
  __hip_bfloat16* zp = z + (size_t)n * 128 * HWP + p;
  #pragma unroll 4
  for (int o = 0; o < 128; o++) {
    const float* wo = sw + o * 64;
    float s0 = 0, s1 = 0, s2 = 0, s3 = 0;
    #pragma unroll
    for (int i = 0; i < 64; i += 4) {
      s0 += wo[i] * v[i];     s1 += wo[i + 1] * v[i + 1];
      s2 += wo[i + 2] * v[i + 2]; s3 += wo[i + 3] * v[i + 3];
    }
    zp[(size_t)o * HWP] = __float2bfloat16((s0 + s1) + (s2 + s3) + sc[o]);
  }
}

// ---------------- depthwise 3x3 + SimpleGate + partial global pool ----------
__global__ __launch_bounds__(256) void dwgate_kernel(
    const __hip_bfloat16* __restrict__ z, const float* __restrict__ dww,
    const float* __restrict__ dwb, __hip_bfloat16* __restrict__ t,
    float* __restrict__ pooled) {
  int plane = blockIdx.y;            // n*64 + c
  int n = plane >> 6, c = plane & 63;
  const __hip_bfloat16* z0 = z + ((size_t)n * 128 + c) * HWP;
  const __hip_bfloat16* z1 = z0 + (size_t)64 * HWP;
  float w0[9], w1[9];
  #pragma unroll
  for (int k = 0; k < 9; k++) { w0[k] = dww[c * 9 + k]; w1[k] = dww[(c + 64) * 9 + k]; }
  float b0 = dwb[c], b1v = dwb[c + 64];
  float lsum = 0.f;
  int base = blockIdx.x * 1024;
  __hip_bfloat16* tp = t + (size_t)plane * HWP;
  for (int k = 0; k < 4; k++) {
    int p = base + k * 256 + threadIdx.x;
    int h = p >> 8, w = p & 255;
    float acc0 = b0, acc1 = b1v;
    #pragma unroll
    for (int dh = -1; dh <= 1; dh++) {
      int hh = h + dh;
      if ((unsigned)hh >= 256u) continue;
      #pragma unroll
      for (int dw_ = -1; dw_ <= 1; dw_++) {
        int ww = w + dw_;
        if ((unsigned)ww >= 256u) continue;
        int q = hh * 256 + ww;
        int ki = (dh + 1) * 3 + (dw_ + 1);
        acc0 += w0[ki] * __bfloat162float(z0[q]);
        acc1 += w1[ki] * __bfloat162float(z1[q]);
      }
    }
    float tv = acc0 * acc1;
    tp[p] = __float2bfloat16(tv);
    lsum += tv;
  }
  for (int off = 32; off; off >>= 1) lsum += __shfl_down(lsum, off);
  __shared__ float ls[4];
  int wid = threadIdx.x >> 6, lid = threadIdx.x & 63;
  if (lid == 0) ls[wid] = lsum;
  __syncthreads();
  if (threadIdx.x == 0) atomicAdd(&pooled[plane], ls[0] + ls[1] + ls[2] + ls[3]);
}

// ---------------- SCA: sigmoid(sca_w @ pooled_mean + sca_b) -----------------
__global__ void sca_kernel(const float* __restrict__ pooled, const float* __restrict__ sw,
                           const float* __restrict__ sb, float* __restrict__ sca) {
  int idx = blockIdx.x * blockDim.x + threadIdx.x;   // n*64 + o
  if (idx >= 512) return;
  int n = idx >> 6, o = idx & 63;
  float s = sb[o];
  const float* pm = pooled + n * 64;
  for (int i = 0; i < 64; i++) s += sw[o * 64 + i] * pm[i] * (1.f / 65536.f);
  sca[idx] = 1.f / (1.f + expf(-s));
}

// -------- fold SCA scale + beta1 into pw2 weights ---------------------------
__global__ void fold_pw2_kernel(const float* __restrict__ w, const float* __restrict__ pb,
                                const float* __restrict__ sca, const float* __restrict__ beta1,
                                float* __restrict__ wf, float* __restrict__ cf) {
  int idx = blockIdx.x * blockDim.x + threadIdx.x;   // n*64 + o
  if (idx >= 512) return;
  int n = idx >> 6, o = idx & 63;
  float bt = beta1[o];
  const float* sn = sca + n * 64;
  float* wfo = wf + (size_t)idx * 64;
  for (int i = 0; i < 64; i++) wfo[i] = bt * w[o * 64 + i] * sn[i];
  cf[idx] = bt * pb[o];
}

// ---------------- pw2 + residual: x1 = x + W2' @ t + c2' -------------------
__global__ __launch_bounds__(256) void pw2_res_kernel(
    const __hip_bfloat16* __restrict__ t, const float* __restrict__ x,
    const float* __restrict__ wf, const float* __restrict__ cf,
    float* __restrict__ x1) {
  __shared__ float sw2[64 * 64];
  __shared__ float sc2[64];
  int n = blockIdx.y;
  const float* wfn = wf + (size_t)n * 64 * 64;
  for (int i = threadIdx.x; i < 64 * 64; i += 256) sw2[i] = wfn[i];
  if (threadIdx.x < 64) sc2[threadIdx.x] = cf[n * 64 + threadIdx.x];
  __syncthreads();
  int p = blockIdx.x * 256 + threadIdx.x;
  const __hip_bfloat16* tn = t + (size_t)n * 64 * HWP + p;
  float v[64];
  #pragma unroll
  for (int i = 0; i < 64; i++) v[i] = __bfloat162float(tn[(size_t)i * HWP]);
  const float* xn = x + (size_t)n * 64 * HWP + p;
  float* x1n = x1 + (size_t)n * 64 * HWP + p;
  #pragma unroll 4
  for (int o = 0; o < 64; o++) {
    const float* wo = sw2 + o * 64;
    float s0 = 0, s1 = 0, s2 = 0, s3 = 0;
    #pragma unroll
    for (int i = 0; i < 64; i += 4) {
      s0 += wo[i] * v[i];     s1 += wo[i + 1] * v[i + 1];
      s2 += wo[i + 2] * v[i + 2]; s3 += wo[i + 3] * v[i + 3];
    }
    x1n[(size_t)o * HWP] = xn[(size_t)o * HWP] + (s0 + s1) + (s2 + s3) + sc2[o];
  }
}

// -------- final: out = x1 + beta2 * pw4(gate(W3' @ x1 + c3)) ---------------
__global__ __launch_bounds__(256) void final_kernel(
    const float* __restrict__ x1, const float* __restrict__ w3f,
    const float* __restrict__ c3f, const float* __restrict__ w4,
    const float* __restrict__ pb4, const float* __restrict__ beta2,
    float* __restrict__ out) {
  __shared__ float sw3[128 * 64];
  __shared__ float sc3[128];
  __shared__ float sw4[64 * 64];
  __shared__ float sb2[64];
  __shared__ float sb4[64];
  int n = blockIdx.y;
  const float* wfn = w3f + (size_t)n * 128 * 64;
  for (int i = threadIdx.x; i < 128 * 64; i += 256) sw3[i] = wfn[i];
  for (int i = threadIdx.x; i < 64 * 64; i += 256) sw4[i] = w4[i];
  if (threadIdx.x < 128) sc3[threadIdx.x] = c3f[n * 128 + threadIdx.x];
  if (threadIdx.x < 64) { sb2[threadIdx.x] = beta2[threadIdx.x]; sb4[threadIdx.x] = pb4[threadIdx.x]; }
  __syncthreads();
  int p = blockIdx.x * 256 + threadIdx.x;
  const float* xn = x1 + (size_t)n * 64 * HWP + p;
  float v[64];
  #pragma unroll
  for (int i = 0; i < 64; i++) v[i] = xn[(size_t)i * HWP];
  float acc[64];
  #pragma unroll
  for (int o = 0; o < 64; o++) acc[o] = 0.f;
  #pragma unroll 2
  for (int j = 0; j < 64; j++) {
    const float* wa = sw3 + j * 64;
    const float* wb = sw3 + (j + 64) * 64;
    float a0 = 0, a1 = 0, a2 = 0, a3 = 0, b0 = 0, b1 = 0, b2 = 0, b3 = 0;
    #pragma unroll
    for (int i = 0; i < 64; i += 4) {
      a0 += wa[i] * v[i];       a1 += wa[i + 1] * v[i + 1];
      a2 += wa[i + 2] * v[i + 2]; a3 += wa[i + 3] * v[i + 3];
      b0 += wb[i] * v[i];       b1 += wb[i + 1] * v[i + 1];
      b2 += wb[i + 2] * v[i + 2]; b3 += wb[i + 3] * v[i + 3];
    }
    float g = ((a0 + a1) + (a2 + a3) + sc3[j]) * ((b0 + b1) + (b2 + b3) + sc3[j + 64]);
    #pragma unroll
    for (int o = 0; o < 64; o++) acc[o] += sw4[o * 64 + j] * g;
  }
  float* on = out + (size_t)n * 64 * HWP + p;
  #pragma unroll
  for (int o = 0; o < 64; o++) on[(size_t)o * HWP] = v[o] + sb2[o] * (acc[o] + sb4[o]);
}

extern "C" void kernel_launch(void* const* d_in, const int* in_sizes, int n_in,
                              void* d_out, int out_size, void* d_ws, size_t ws_size,
                              hipStream_t stream) {
  const float* x    = (const float*)d_in[0];
  const float* ln1w = (const float*)d_in[1];
  const float* ln1b = (const float*)d_in[2];
  const float* pw1w = (const float*)d_in[3];
  const float* pw1b = (const float*)d_in[4];
  const float* dww  = (const float*)d_in[5];
  const float* dwb  = (const float*)d_in[6];
  const float* scaw = (const float*)d_in[7];
  const float* scab = (const float*)d_in[8];
  const float* pw2w = (const float*)d_in[9];
  const float* pw2b = (const float*)d_in[10];
  const float* ln2w = (const float*)d_in[11];
  const float* ln2b = (const float*)d_in[12];
  const float* pw3w = (const float*)d_in[13];
  const float* pw3b = (const float*)d_in[14];
  const float* pw4w = (const float*)d_in[15];
  const float* pw4b = (const float*)d_in[16];
  const float* beta1= (const float*)d_in[17];
  const float* beta2= (const float*)d_in[18];
  float* out = (float*)d_out;

  // Workspace layout: region A (134 MB) holds z (bf16, live K3) then x1 (fp32,
  // written K5 after z is dead — safe overlap). Region B (67 MB): t (bf16).
  char* ws = (char*)d_ws;
  __hip_bfloat16* z  = (__hip_bfloat16*)ws;
  float*          x1 = (float*)ws;
  __hip_bfloat16* t  = (__hip_bfloat16*)(ws + 134217728ull);
  float* sm = (float*)(ws + 134217728ull + 67108864ull);
  float* a1 = sm;            float* b1 = a1 + 512;
  float* w1f = b1 + 512;     float* c1f = w1f + 65536;
  float* pooled = c1f + 1024; float* sca = pooled + 512;
  float* w2f = sca + 512;    float* c2f = w2f + 32768;
  float* a2 = c2f + 512;     float* b2 = a2 + 512;
  float* w3f = b2 + 512;     float* c3f = w3f + 65536;

  hipMemsetAsync(pooled, 0, 512 * sizeof(float), stream);

  hipLaunchKernelGGL(ln_stats_kernel, dim3(512), dim3(256), 0, stream, x, ln1w, ln1b, a1, b1);
  hipLaunchKernelGGL(fold_kernel, dim3(4), dim3(256), 0, stream, pw1w, pw1b, a1, b1, w1f, c1f, 128);
  hipLaunchKernelGGL(pw1_kernel, dim3(256, 8), dim3(256), 0, stream, x, w1f, c1f, z);
  hipLaunchKernelGGL(dwgate_kernel, dim3(64, 512), dim3(256), 0, stream, z, dww, dwb, t, pooled);
  hipLaunchKernelGGL(sca_kernel, dim3(2), dim3(256), 0, stream, pooled, scaw, scab, sca);
  hipLaunchKernelGGL(fold_pw2_kernel, dim3(2), dim3(256), 0, stream, pw2w, pw2b, sca, beta1, w2f, c2f);
  hipLaunchKernelGGL(pw2_res_kernel, dim3(256, 8), dim3(256), 0, stream, t, x, w2f, c2f, x1);
  hipLaunchKernelGGL(ln_stats_kernel, dim3(512), dim3(256), 0, stream, x1, ln2w, ln2b, a2, b2);
  hipLaunchKernelGGL(fold_kernel, dim3(4), dim3(256), 0, stream, pw3w, pw3b, a2, b2, w3f, c3f, 128);
  hipLaunchKernelGGL(final_kernel, dim3(256, 8), dim3(256), 0, stream, x1, w3f, c3f, pw4w, pw4b, beta2, out);
}

// Round 3
// 799.875 us; speedup vs baseline: 2.1761x; 2.1761x over previous
//
#include <hip/hip_runtime.h>
#include <hip/hip_bf16.h>

#define NB 8
#define CC 64
#define HWP 65536          // H*W

typedef __attribute__((ext_vector_type(8))) short short8;
typedef __attribute__((ext_vector_type(4))) float f32x4;

__device__ __forceinline__ short f2bf(float f) {
  union { float f; unsigned u; } v; v.f = f;
  return (short)((v.u + 0x7FFF + ((v.u >> 16) & 1)) >> 16);
}

// ---------------- LN stats: one block per (n,c) plane --------------------
__global__ __launch_bounds__(256) void ln_stats_kernel(
    const float* __restrict__ x, const float* __restrict__ lw,
    const float* __restrict__ lb, float* __restrict__ a, float* __restrict__ b) {
  int plane = blockIdx.x;            // n*64 + c
  int c = plane & 63;
  const float4* p4 = (const float4*)(x + (size_t)plane * HWP);
  float s = 0.f, s2 = 0.f;
  for (int i = threadIdx.x; i < HWP / 4; i += 256) {
    float4 v = p4[i];
    s  += v.x + v.y + v.z + v.w;
    s2 += v.x * v.x + v.y * v.y + v.z * v.z + v.w * v.w;
  }
  for (int off = 32; off; off >>= 1) {
    s  += __shfl_down(s, off);
    s2 += __shfl_down(s2, off);
  }
  __shared__ float ls[4], ls2[4];
  int wid = threadIdx.x >> 6, lid = threadIdx.x & 63;
  if (lid == 0) { ls[wid] = s; ls2[wid] = s2; }
  __syncthreads();
  if (threadIdx.x == 0) {
    float S  = ls[0] + ls[1] + ls[2] + ls[3];
    float S2 = ls2[0] + ls2[1] + ls2[2] + ls2[3];
    float mean = S * (1.f / (float)HWP);
    float var  = S2 * (1.f / (float)HWP) - mean * mean;
    float rstd = rsqrtf(var + 1e-6f);
    float av = rstd * lw[c];
    a[plane] = av;
    b[plane] = lb[c] - mean * av;
  }
}

// -------- fold LN into pw weights -----------------------------------------
__global__ void fold_kernel(const float* __restrict__ w, const float* __restrict__ pb,
                            const float* __restrict__ a, const float* __restrict__ b,
                            float* __restrict__ wf, float* __restrict__ cf, int O) {
  int idx = blockIdx.x * blockDim.x + threadIdx.x;   // n*O + o
  if (idx >= NB * O) return;
  int n = idx / O, o = idx - n * O;
  const float* an = a + n * 64;
  const float* bn = b + n * 64;
  const float* wo = w + o * 64;
  float* wfo = wf + (size_t)idx * 64;
  float cc = pb[o];
  for (int i = 0; i < 64; i++) { float wv = wo[i]; wfo[i] = wv * an[i]; cc += wv * bn[i]; }
  cf[idx] = cc;
}

// ---------------- pw1 via MFMA: z[n,o,p] = W1'[n] @ x[n] + c1', M=128 -----
__global__ __launch_bounds__(256, 2) void gemm_pw1_kernel(
    const float* __restrict__ x, const float* __restrict__ wf,
    const float* __restrict__ cf, unsigned short* __restrict__ z) {
  int n = blockIdx.y;
  int lane = threadIdx.x & 63, wid = threadIdx.x >> 6;
  int col = lane & 15, quad = lane >> 4;
  short8 a[8][2];
  const float* wfn = wf + (size_t)n * 128 * 64;
  #pragma unroll
  for (int mt = 0; mt < 8; mt++)
    #pragma unroll
    for (int ks = 0; ks < 2; ks++) {
      const float* wp = wfn + (mt * 16 + col) * 64 + ks * 32 + quad * 8;
      short8 v;
      #pragma unroll
      for (int j = 0; j < 8; j++) v[j] = f2bf(wp[j]);
      a[mt][ks] = v;
    }
  float cb[8][4];
  #pragma unroll
  for (int mt = 0; mt < 8; mt++)
    #pragma unroll
    for (int r = 0; r < 4; r++) cb[mt][r] = cf[n * 128 + mt * 16 + quad * 4 + r];
  const float* xn = x + (size_t)n * 64 * HWP;
  unsigned short* zn = z + (size_t)n * 128 * HWP;
  int pxbase = blockIdx.x * 512 + wid * 16 + col;
  for (int tile = 0; tile < 8; tile++) {
    int p = pxbase + tile * 64;
    short8 b[2];
    #pragma unroll
    for (int ks = 0; ks < 2; ks++)
      #pragma unroll
      for (int j = 0; j < 8; j++)
        b[ks][j] = f2bf(xn[(size_t)(ks * 32 + quad * 8 + j) * HWP + p]);
    f32x4 acc[8];
    #pragma unroll
    for (int mt = 0; mt < 8; mt++) {
      acc[mt] = (f32x4){0.f, 0.f, 0.f, 0.f};
      acc[mt] = __builtin_amdgcn_mfma_f32_16x16x32_bf16(a[mt][0], b[0], acc[mt], 0, 0, 0);
      acc[mt] = __builtin_amdgcn_mfma_f32_16x16x32_bf16(a[mt][1], b[1], acc[mt], 0, 0, 0);
    }
    #pragma unroll
    for (int mt = 0; mt < 8; mt++)
      #pragma unroll
      for (int r = 0; r < 4; r++)
        zn[(size_t)(mt * 16 + quad * 4 + r) * HWP + p] =
            (unsigned short)f2bf(acc[mt][r] + cb[mt][r]);
  }
}

// ---------------- depthwise 3x3 + SimpleGate + partial global pool ----------
__global__ __launch_bounds__(256) void dwgate_kernel(
    const __hip_bfloat16* __restrict__ z, const float* __restrict__ dww,
    const float* __restrict__ dwb, __hip_bfloat16* __restrict__ t,
    float* __restrict__ pooled) {
  int plane = blockIdx.y;            // n*64 + c
  int n = plane >> 6, c = plane & 63;
  const __hip_bfloat16* z0 = z + ((size_t)n * 128 + c) * HWP;
  const __hip_bfloat16* z1 = z0 + (size_t)64 * HWP;
  float w0[9], w1[9];
  #pragma unroll
  for (int k = 0; k < 9; k++) { w0[k] = dww[c * 9 + k]; w1[k] = dww[(c + 64) * 9 + k]; }
  float b0 = dwb[c], b1v = dwb[c + 64];
  float lsum = 0.f;
  int base = blockIdx.x * 1024;
  __hip_bfloat16* tp = t + (size_t)plane * HWP;
  for (int k = 0; k < 4; k++) {
    int p = base + k * 256 + threadIdx.x;
    int h = p >> 8, w = p & 255;
    float acc0 = b0, acc1 = b1v;
    #pragma unroll
    for (int dh = -1; dh <= 1; dh++) {
      int hh = h + dh;
      if ((unsigned)hh >= 256u) continue;
      #pragma unroll
      for (int dw_ = -1; dw_ <= 1; dw_++) {
        int ww = w + dw_;
        if ((unsigned)ww >= 256u) continue;
        int q = hh * 256 + ww;
        int ki = (dh + 1) * 3 + (dw_ + 1);
        acc0 += w0[ki] * __bfloat162float(z0[q]);
        acc1 += w1[ki] * __bfloat162float(z1[q]);
      }
    }
    float tv = acc0 * acc1;
    tp[p] = __float2bfloat16(tv);
    lsum += tv;
  }
  for (int off = 32; off; off >>= 1) lsum += __shfl_down(lsum, off);
  __shared__ float ls[4];
  int wid = threadIdx.x >> 6, lid = threadIdx.x & 63;
  if (lid == 0) ls[wid] = lsum;
  __syncthreads();
  if (threadIdx.x == 0) atomicAdd(&pooled[plane], ls[0] + ls[1] + ls[2] + ls[3]);
}

// ---------------- SCA ------------------------------------------------------
__global__ void sca_kernel(const float* __restrict__ pooled, const float* __restrict__ sw,
                           const float* __restrict__ sb, float* __restrict__ sca) {
  int idx = blockIdx.x * blockDim.x + threadIdx.x;   // n*64 + o
  if (idx >= 512) return;
  int n = idx >> 6, o = idx & 63;
  float s = sb[o];
  const float* pm = pooled + n * 64;
  for (int i = 0; i < 64; i++) s += sw[o * 64 + i] * pm[i] * (1.f / 65536.f);
  sca[idx] = 1.f / (1.f + expf(-s));
}

// -------- fold SCA scale + beta1 into pw2 weights ---------------------------
__global__ void fold_pw2_kernel(const float* __restrict__ w, const float* __restrict__ pb,
                                const float* __restrict__ sca, const float* __restrict__ beta1,
                                float* __restrict__ wf, float* __restrict__ cf) {
  int idx = blockIdx.x * blockDim.x + threadIdx.x;   // n*64 + o
  if (idx >= 512) return;
  int n = idx >> 6, o = idx & 63;
  float bt = beta1[o];
  const float* sn = sca + n * 64;
  float* wfo = wf + (size_t)idx * 64;
  for (int i = 0; i < 64; i++) wfo[i] = bt * w[o * 64 + i] * sn[i];
  cf[idx] = bt * pb[o];
}

// ---------------- pw2 + residual via MFMA: x1 = x + W2' @ t + c2', M=64 ----
__global__ __launch_bounds__(256, 2) void gemm_pw2_kernel(
    const unsigned short* __restrict__ t, const float* __restrict__ x,
    const float* __restrict__ wf, const float* __restrict__ cf,
    float* __restrict__ x1) {
  int n = blockIdx.y;
  int lane = threadIdx.x & 63, wid = threadIdx.x >> 6;
  int col = lane & 15, quad = lane >> 4;
  short8 a[4][2];
  const float* wfn = wf + (size_t)n * 64 * 64;
  #pragma unroll
  for (int mt = 0; mt < 4; mt++)
    #pragma unroll
    for (int ks = 0; ks < 2; ks++) {
      const float* wp = wfn + (mt * 16 + col) * 64 + ks * 32 + quad * 8;
      short8 v;
      #pragma unroll
      for (int j = 0; j < 8; j++) v[j] = f2bf(wp[j]);
      a[mt][ks] = v;
    }
  float cb[4][4];
  #pragma unroll
  for (int mt = 0; mt < 4; mt++)
    #pragma unroll
    for (int r = 0; r < 4; r++) cb[mt][r] = cf[n * 64 + mt * 16 + quad * 4 + r];
  const unsigned short* tn = t + (size_t)n * 64 * HWP;
  const float* xn = x + (size_t)n * 64 * HWP;
  float* x1n = x1 + (size_t)n * 64 * HWP;
  int pxbase = blockIdx.x * 512 + wid * 16 + col;
  for (int tile = 0; tile < 8; tile++) {
    int p = pxbase + tile * 64;
    short8 b[2];
    #pragma unroll
    for (int ks = 0; ks < 2; ks++)
      #pragma unroll
      for (int j = 0; j < 8; j++)
        b[ks][j] = (short)tn[(size_t)(ks * 32 + quad * 8 + j) * HWP + p];
    f32x4 acc[4];
    #pragma unroll
    for (int mt = 0; mt < 4; mt++) {
      acc[mt] = (f32x4){0.f, 0.f, 0.f, 0.f};
      acc[mt] = __builtin_amdgcn_mfma_f32_16x16x32_bf16(a[mt][0], b[0], acc[mt], 0, 0, 0);
      acc[mt] = __builtin_amdgcn_mfma_f32_16x16x32_bf16(a[mt][1], b[1], acc[mt], 0, 0, 0);
    }
    #pragma unroll
    for (int mt = 0; mt < 4; mt++)
      #pragma unroll
      for (int r = 0; r < 4; r++) {
        size_t idx = (size_t)(mt * 16 + quad * 4 + r) * HWP + p;
        x1n[idx] = xn[idx] + acc[mt][r] + cb[mt][r];
      }
  }
}

// -------- final via chained MFMA: out = x1 + b2*(W4 @ gate(W3' @ x1 + c3) + c4)
// LDS transpose of the gate output g: written AND read as dwords (no type
// punning), bracketed by __syncthreads() so the write->read and
// read->next-write orders are compiler- and hardware-enforced.
__global__ __launch_bounds__(256, 2) void final_mfma_kernel(
    const float* __restrict__ x1, const float* __restrict__ w3f,
    const float* __restrict__ c3f, const float* __restrict__ w4,
    const float* __restrict__ pb4, const float* __restrict__ beta2,
    float* __restrict__ out) {
  __shared__ float s_c3[128];
  __shared__ float s_b2[64];
  __shared__ float s_c4[64];
  __shared__ __align__(16) unsigned g_lds[64 * 33];  // [pixel][j/2], stride 33 dwords
  int n = blockIdx.y;
  int lane = threadIdx.x & 63, wid = threadIdx.x >> 6;
  int col = lane & 15, quad = lane >> 4;
  if (threadIdx.x < 128) s_c3[threadIdx.x] = c3f[n * 128 + threadIdx.x];
  if (threadIdx.x < 64) { s_b2[threadIdx.x] = beta2[threadIdx.x]; s_c4[threadIdx.x] = pb4[threadIdx.x]; }
  short8 a3[8][2];
  const float* wfn = w3f + (size_t)n * 128 * 64;
  #pragma unroll
  for (int mt = 0; mt < 8; mt++)
    #pragma unroll
    for (int ks = 0; ks < 2; ks++) {
      const float* wp = wfn + (mt * 16 + col) * 64 + ks * 32 + quad * 8;
      short8 v;
      #pragma unroll
      for (int j = 0; j < 8; j++) v[j] = f2bf(wp[j]);
      a3[mt][ks] = v;
    }
  short8 a4[4][2];
  #pragma unroll
  for (int mt = 0; mt < 4; mt++)
    #pragma unroll
    for (int ks = 0; ks < 2; ks++) {
      const float* wp = w4 + (mt * 16 + col) * 64 + ks * 32 + quad * 8;
      short8 v;
      #pragma unroll
      for (int j = 0; j < 8; j++) v[j] = f2bf(wp[j]);
      a4[mt][ks] = v;
    }
  __syncthreads();
  const float* x1n = x1 + (size_t)n * 64 * HWP;
  float* outn = out + (size_t)n * 64 * HWP;
  int pxbase = blockIdx.x * 512 + wid * 16 + col;
  unsigned* grow = g_lds + (wid * 16 + col) * 33;    // this lane's pixel row
  for (int tile = 0; tile < 8; tile++) {
    int p = pxbase + tile * 64;
    // B1 fragments from x1 (fp32 -> bf16)
    short8 b1[2];
    #pragma unroll
    for (int ks = 0; ks < 2; ks++)
      #pragma unroll
      for (int j = 0; j < 8; j++)
        b1[ks][j] = f2bf(x1n[(size_t)(ks * 32 + quad * 8 + j) * HWP + p]);
    // G1: y3 = W3' @ x1 (128 rows)
    f32x4 acc[8];
    #pragma unroll
    for (int mt = 0; mt < 8; mt++) {
      acc[mt] = (f32x4){0.f, 0.f, 0.f, 0.f};
      acc[mt] = __builtin_amdgcn_mfma_f32_16x16x32_bf16(a3[mt][0], b1[0], acc[mt], 0, 0, 0);
      acc[mt] = __builtin_amdgcn_mfma_f32_16x16x32_bf16(a3[mt][1], b1[1], acc[mt], 0, 0, 0);
    }
    // gate: g[j] = (y3[j]+c3[j]) * (y3[j+64]+c3[j+64]); pack pairs as dwords
    #pragma unroll
    for (int mt = 0; mt < 4; mt++)
      #pragma unroll
      for (int rr = 0; rr < 2; rr++) {
        int j0 = mt * 16 + quad * 4 + rr * 2;
        float ga = (acc[mt][rr * 2]     + s_c3[j0])     * (acc[mt + 4][rr * 2]     + s_c3[64 + j0]);
        float gb = (acc[mt][rr * 2 + 1] + s_c3[j0 + 1]) * (acc[mt + 4][rr * 2 + 1] + s_c3[64 + j0 + 1]);
        unsigned lo = (unsigned short)f2bf(ga);
        unsigned hi = (unsigned short)f2bf(gb);
        grow[j0 >> 1] = lo | (hi << 16);
      }
    __syncthreads();
    // B2 fragments from g (LDS dword reads, same type as writes)
    short8 b2[2];
    #pragma unroll
    for (int ks = 0; ks < 2; ks++)
      #pragma unroll
      for (int w = 0; w < 4; w++) {
        unsigned u = grow[ks * 16 + quad * 4 + w];
        b2[ks][2 * w]     = (short)(u & 0xFFFFu);
        b2[ks][2 * w + 1] = (short)(u >> 16);
      }
    __syncthreads();
    // G2: y4 = W4 @ g (64 rows)
    f32x4 acc2[4];
    #pragma unroll
    for (int mt = 0; mt < 4; mt++) {
      acc2[mt] = (f32x4){0.f, 0.f, 0.f, 0.f};
      acc2[mt] = __builtin_amdgcn_mfma_f32_16x16x32_bf16(a4[mt][0], b2[0], acc2[mt], 0, 0, 0);
      acc2[mt] = __builtin_amdgcn_mfma_f32_16x16x32_bf16(a4[mt][1], b2[1], acc2[mt], 0, 0, 0);
    }
    // epilogue: out = x1 + beta2*(y4 + c4)
    #pragma unroll
    for (int mt = 0; mt < 4; mt++)
      #pragma unroll
      for (int r = 0; r < 4; r++) {
        int o = mt * 16 + quad * 4 + r;
        size_t idx = (size_t)o * HWP + p;
        outn[idx] = x1n[idx] + s_b2[o] * (acc2[mt][r] + s_c4[o]);
      }
  }
}

extern "C" void kernel_launch(void* const* d_in, const int* in_sizes, int n_in,
                              void* d_out, int out_size, void* d_ws, size_t ws_size,
                              hipStream_t stream) {
  const float* x    = (const float*)d_in[0];
  const float* ln1w = (const float*)d_in[1];
  const float* ln1b = (const float*)d_in[2];
  const float* pw1w = (const float*)d_in[3];
  const float* pw1b = (const float*)d_in[4];
  const float* dww  = (const float*)d_in[5];
  const float* dwb  = (const float*)d_in[6];
  const float* scaw = (const float*)d_in[7];
  const float* scab = (const float*)d_in[8];
  const float* pw2w = (const float*)d_in[9];
  const float* pw2b = (const float*)d_in[10];
  const float* ln2w = (const float*)d_in[11];
  const float* ln2b = (const float*)d_in[12];
  const float* pw3w = (const float*)d_in[13];
  const float* pw3b = (const float*)d_in[14];
  const float* pw4w = (const float*)d_in[15];
  const float* pw4b = (const float*)d_in[16];
  const float* beta1= (const float*)d_in[17];
  const float* beta2= (const float*)d_in[18];
  float* out = (float*)d_out;

  char* ws = (char*)d_ws;
  unsigned short* z  = (unsigned short*)ws;          // bf16 bits, 134 MB
  float*          x1 = (float*)ws;                    // reuses z region (z dead)
  unsigned short* t  = (unsigned short*)(ws + 134217728ull);  // bf16 bits, 67 MB
  float* sm = (float*)(ws + 134217728ull + 67108864ull);
  float* a1 = sm;            float* b1 = a1 + 512;
  float* w1f = b1 + 512;     float* c1f = w1f + 65536;
  float* pooled = c1f + 1024; float* sca = pooled + 512;
  float* w2f = sca + 512;    float* c2f = w2f + 32768;
  float* a2 = c2f + 512;     float* b2 = a2 + 512;
  float* w3f = b2 + 512;     float* c3f = w3f + 65536;

  hipMemsetAsync(pooled, 0, 512 * sizeof(float), stream);

  hipLaunchKernelGGL(ln_stats_kernel, dim3(512), dim3(256), 0, stream, x, ln1w, ln1b, a1, b1);
  hipLaunchKernelGGL(fold_kernel, dim3(4), dim3(256), 0, stream, pw1w, pw1b, a1, b1, w1f, c1f, 128);
  hipLaunchKernelGGL(gemm_pw1_kernel, dim3(128, 8), dim3(256), 0, stream, x, w1f, c1f, z);
  hipLaunchKernelGGL(dwgate_kernel, dim3(64, 512), dim3(256), 0, stream,
                     (const __hip_bfloat16*)z, dww, dwb, (__hip_bfloat16*)t, pooled);
  hipLaunchKernelGGL(sca_kernel, dim3(2), dim3(256), 0, stream, pooled, scaw, scab, sca);
  hipLaunchKernelGGL(fold_pw2_kernel, dim3(2), dim3(256), 0, stream, pw2w, pw2b, sca, beta1, w2f, c2f);
  hipLaunchKernelGGL(gemm_pw2_kernel, dim3(128, 8), dim3(256), 0, stream, t, x, w2f, c2f, x1);
  hipLaunchKernelGGL(ln_stats_kernel, dim3(512), dim3(256), 0, stream, x1, ln2w, ln2b, a2, b2);
  hipLaunchKernelGGL(fold_kernel, dim3(4), dim3(256), 0, stream, pw3w, pw3b, a2, b2, w3f, c3f, 128);
  hipLaunchKernelGGL(final_mfma_kernel, dim3(128, 8), dim3(256), 0, stream,
                     x1, w3f, c3f, pw4w, pw4b, beta2, out);
}

// Round 4
// 676.605 us; speedup vs baseline: 2.5726x; 1.1822x over previous
//
#include <hip/hip_runtime.h>
#include <hip/hip_bf16.h>

#define NB 8
#define CC 64
#define HWP 65536          // H*W

typedef __attribute__((ext_vector_type(8))) short short8;
typedef __attribute__((ext_vector_type(4))) float f32x4;

__device__ __forceinline__ short f2bf(float f) {
  union { float f; unsigned u; } v; v.f = f;
  return (short)((v.u + 0x7FFF + ((v.u >> 16) & 1)) >> 16);
}
__device__ __forceinline__ float bf2f(unsigned short u) {
  union { unsigned u; float f; } v; v.u = ((unsigned)u) << 16; return v.f;
}

// ---------------- LN stats: one block per (n,c) plane --------------------
__global__ __launch_bounds__(256) void ln_stats_kernel(
    const float* __restrict__ x, const float* __restrict__ lw,
    const float* __restrict__ lb, float* __restrict__ a, float* __restrict__ b) {
  int plane = blockIdx.x;            // n*64 + c
  int c = plane & 63;
  const float4* p4 = (const float4*)(x + (size_t)plane * HWP);
  float s = 0.f, s2 = 0.f;
  for (int i = threadIdx.x; i < HWP / 4; i += 256) {
    float4 v = p4[i];
    s  += v.x + v.y + v.z + v.w;
    s2 += v.x * v.x + v.y * v.y + v.z * v.z + v.w * v.w;
  }
  for (int off = 32; off; off >>= 1) {
    s  += __shfl_down(s, off);
    s2 += __shfl_down(s2, off);
  }
  __shared__ float ls[4], ls2[4];
  int wid = threadIdx.x >> 6, lid = threadIdx.x & 63;
  if (lid == 0) { ls[wid] = s; ls2[wid] = s2; }
  __syncthreads();
  if (threadIdx.x == 0) {
    float S  = ls[0] + ls[1] + ls[2] + ls[3];
    float S2 = ls2[0] + ls2[1] + ls2[2] + ls2[3];
    float mean = S * (1.f / (float)HWP);
    float var  = S2 * (1.f / (float)HWP) - mean * mean;
    float rstd = rsqrtf(var + 1e-6f);
    float av = rstd * lw[c];
    a[plane] = av;
    b[plane] = lb[c] - mean * av;
  }
}

// -------- fold LN into pw weights -----------------------------------------
__global__ void fold_kernel(const float* __restrict__ w, const float* __restrict__ pb,
                            const float* __restrict__ a, const float* __restrict__ b,
                            float* __restrict__ wf, float* __restrict__ cf, int O) {
  int idx = blockIdx.x * blockDim.x + threadIdx.x;   // n*O + o
  if (idx >= NB * O) return;
  int n = idx / O, o = idx - n * O;
  const float* an = a + n * 64;
  const float* bn = b + n * 64;
  const float* wo = w + o * 64;
  float* wfo = wf + (size_t)idx * 64;
  float cc = pb[o];
  for (int i = 0; i < 64; i++) { float wv = wo[i]; wfo[i] = wv * an[i]; cc += wv * bn[i]; }
  cf[idx] = cc;
}

// ---------------- pw1 via MFMA: z[n,o,p] = W1'[n] @ x[n] + c1', M=128 -----
__global__ __launch_bounds__(256, 2) void gemm_pw1_kernel(
    const float* __restrict__ x, const float* __restrict__ wf,
    const float* __restrict__ cf, unsigned short* __restrict__ z) {
  int n = blockIdx.y;
  int lane = threadIdx.x & 63, wid = threadIdx.x >> 6;
  int col = lane & 15, quad = lane >> 4;
  short8 a[8][2];
  const float* wfn = wf + (size_t)n * 128 * 64;
  #pragma unroll
  for (int mt = 0; mt < 8; mt++)
    #pragma unroll
    for (int ks = 0; ks < 2; ks++) {
      const float* wp = wfn + (mt * 16 + col) * 64 + ks * 32 + quad * 8;
      short8 v;
      #pragma unroll
      for (int j = 0; j < 8; j++) v[j] = f2bf(wp[j]);
      a[mt][ks] = v;
    }
  float cb[8][4];
  #pragma unroll
  for (int mt = 0; mt < 8; mt++)
    #pragma unroll
    for (int r = 0; r < 4; r++) cb[mt][r] = cf[n * 128 + mt * 16 + quad * 4 + r];
  const float* xn = x + (size_t)n * 64 * HWP;
  unsigned short* zn = z + (size_t)n * 128 * HWP;
  int pxbase = blockIdx.x * 512 + wid * 16 + col;
  for (int tile = 0; tile < 8; tile++) {
    int p = pxbase + tile * 64;
    short8 b[2];
    #pragma unroll
    for (int ks = 0; ks < 2; ks++)
      #pragma unroll
      for (int j = 0; j < 8; j++)
        b[ks][j] = f2bf(xn[(size_t)(ks * 32 + quad * 8 + j) * HWP + p]);
    f32x4 acc[8];
    #pragma unroll
    for (int mt = 0; mt < 8; mt++) {
      acc[mt] = (f32x4){0.f, 0.f, 0.f, 0.f};
      acc[mt] = __builtin_amdgcn_mfma_f32_16x16x32_bf16(a[mt][0], b[0], acc[mt], 0, 0, 0);
      acc[mt] = __builtin_amdgcn_mfma_f32_16x16x32_bf16(a[mt][1], b[1], acc[mt], 0, 0, 0);
    }
    #pragma unroll
    for (int mt = 0; mt < 8; mt++)
      #pragma unroll
      for (int r = 0; r < 4; r++)
        zn[(size_t)(mt * 16 + quad * 4 + r) * HWP + p] =
            (unsigned short)f2bf(acc[mt][r] + cb[mt][r]);
  }
}

// ---- depthwise 3x3 + SimpleGate + pool: row-streaming stencil ------------
// One block per (n,c) plane. 4 waves x 64-row bands. A wave covers a full
// 256-px row: 64 lanes x 4 px (ushort4 = 8B loads). Rolling 3-row register
// window per plane; halo pixels carried via shuffle at row-load time.
__global__ __launch_bounds__(256) void dwgate_kernel(
    const unsigned short* __restrict__ z, const float* __restrict__ dww,
    const float* __restrict__ dwb, unsigned short* __restrict__ t,
    float* __restrict__ pooled) {
  int plane = blockIdx.x;            // n*64 + c
  int n = plane >> 6, c = plane & 63;
  int lane = threadIdx.x & 63, wv = threadIdx.x >> 6;
  const unsigned short* z0 = z + ((size_t)n * 128 + c) * HWP;
  const unsigned short* z1 = z0 + (size_t)64 * HWP;
  unsigned short* tp = t + (size_t)plane * HWP;
  float w0[9], w1[9];
  #pragma unroll
  for (int k = 0; k < 9; k++) { w0[k] = dww[c * 9 + k]; w1[k] = dww[(c + 64) * 9 + k]; }
  float bias0 = dwb[c], bias1 = dwb[c + 64];
  int r0 = wv * 64;
  int colb = lane * 4;

  // row registers: [plane][window slot] -> 4 px + left/right halo
  float fa[3][4], la[3], ra[3];      // z0: slots prev, cur, next
  float fb[3][4], lb_[3], rb[3];     // z1

  auto loadrow = [&](const unsigned short* base, int h, float* f, float& l, float& r) {
    if ((unsigned)h < 256u) {
      ushort4 u = *(const ushort4*)(base + h * 256 + colb);
      f[0] = bf2f(u.x); f[1] = bf2f(u.y); f[2] = bf2f(u.z); f[3] = bf2f(u.w);
    } else {
      f[0] = f[1] = f[2] = f[3] = 0.f;
    }
    float ll = __shfl_up(f[3], 1);
    float rr = __shfl_down(f[0], 1);
    l = (lane == 0) ? 0.f : ll;
    r = (lane == 63) ? 0.f : rr;
  };

  loadrow(z0, r0 - 1, fa[0], la[0], ra[0]);
  loadrow(z1, r0 - 1, fb[0], lb_[0], rb[0]);
  loadrow(z0, r0,     fa[1], la[1], ra[1]);
  loadrow(z1, r0,     fb[1], lb_[1], rb[1]);

  float lsum = 0.f;
  #pragma unroll 2
  for (int h = r0; h < r0 + 64; h++) {
    loadrow(z0, h + 1, fa[2], la[2], ra[2]);
    loadrow(z1, h + 1, fb[2], lb_[2], rb[2]);
    float o0[4] = {bias0, bias0, bias0, bias0};
    float o1[4] = {bias1, bias1, bias1, bias1};
    #pragma unroll
    for (int rr_ = 0; rr_ < 3; rr_++) {
      float wl0 = w0[rr_ * 3], wc0 = w0[rr_ * 3 + 1], wr0 = w0[rr_ * 3 + 2];
      float wl1 = w1[rr_ * 3], wc1 = w1[rr_ * 3 + 1], wr1 = w1[rr_ * 3 + 2];
      const float* f0 = fa[rr_]; const float* f1 = fb[rr_];
      float l0 = la[rr_], r0h = ra[rr_], l1 = lb_[rr_], r1h = rb[rr_];
      o0[0] += wl0 * l0    + wc0 * f0[0] + wr0 * f0[1];
      o0[1] += wl0 * f0[0] + wc0 * f0[1] + wr0 * f0[2];
      o0[2] += wl0 * f0[1] + wc0 * f0[2] + wr0 * f0[3];
      o0[3] += wl0 * f0[2] + wc0 * f0[3] + wr0 * r0h;
      o1[0] += wl1 * l1    + wc1 * f1[0] + wr1 * f1[1];
      o1[1] += wl1 * f1[0] + wc1 * f1[1] + wr1 * f1[2];
      o1[2] += wl1 * f1[1] + wc1 * f1[2] + wr1 * f1[3];
      o1[3] += wl1 * f1[2] + wc1 * f1[3] + wr1 * r1h;
    }
    float g0 = o0[0] * o1[0], g1 = o0[1] * o1[1];
    float g2 = o0[2] * o1[2], g3 = o0[3] * o1[3];
    uint2 pk;
    pk.x = (unsigned)(unsigned short)f2bf(g0) | ((unsigned)(unsigned short)f2bf(g1) << 16);
    pk.y = (unsigned)(unsigned short)f2bf(g2) | ((unsigned)(unsigned short)f2bf(g3) << 16);
    *(uint2*)(tp + (size_t)h * 256 + colb) = pk;
    lsum += (g0 + g1) + (g2 + g3);
    // rotate window
    #pragma unroll
    for (int i = 0; i < 4; i++) { fa[0][i] = fa[1][i]; fa[1][i] = fa[2][i];
                                  fb[0][i] = fb[1][i]; fb[1][i] = fb[2][i]; }
    la[0] = la[1]; la[1] = la[2]; ra[0] = ra[1]; ra[1] = ra[2];
    lb_[0] = lb_[1]; lb_[1] = lb_[2]; rb[0] = rb[1]; rb[1] = rb[2];
  }
  for (int off = 32; off; off >>= 1) lsum += __shfl_down(lsum, off);
  __shared__ float ls[4];
  if (lane == 0) ls[wv] = lsum;
  __syncthreads();
  if (threadIdx.x == 0) pooled[plane] = ls[0] + ls[1] + ls[2] + ls[3];
}

// ---------------- SCA ------------------------------------------------------
__global__ void sca_kernel(const float* __restrict__ pooled, const float* __restrict__ sw,
                           const float* __restrict__ sb, float* __restrict__ sca) {
  int idx = blockIdx.x * blockDim.x + threadIdx.x;   // n*64 + o
  if (idx >= 512) return;
  int n = idx >> 6, o = idx & 63;
  float s = sb[o];
  const float* pm = pooled + n * 64;
  for (int i = 0; i < 64; i++) s += sw[o * 64 + i] * pm[i] * (1.f / 65536.f);
  sca[idx] = 1.f / (1.f + expf(-s));
}

// -------- fold SCA scale + beta1 into pw2 weights ---------------------------
__global__ void fold_pw2_kernel(const float* __restrict__ w, const float* __restrict__ pb,
                                const float* __restrict__ sca, const float* __restrict__ beta1,
                                float* __restrict__ wf, float* __restrict__ cf) {
  int idx = blockIdx.x * blockDim.x + threadIdx.x;   // n*64 + o
  if (idx >= 512) return;
  int n = idx >> 6, o = idx & 63;
  float bt = beta1[o];
  const float* sn = sca + n * 64;
  float* wfo = wf + (size_t)idx * 64;
  for (int i = 0; i < 64; i++) wfo[i] = bt * w[o * 64 + i] * sn[i];
  cf[idx] = bt * pb[o];
}

// ---------------- pw2 + residual via MFMA: x1 = x + W2' @ t + c2', M=64 ----
__global__ __launch_bounds__(256, 2) void gemm_pw2_kernel(
    const unsigned short* __restrict__ t, const float* __restrict__ x,
    const float* __restrict__ wf, const float* __restrict__ cf,
    float* __restrict__ x1) {
  int n = blockIdx.y;
  int lane = threadIdx.x & 63, wid = threadIdx.x >> 6;
  int col = lane & 15, quad = lane >> 4;
  short8 a[4][2];
  const float* wfn = wf + (size_t)n * 64 * 64;
  #pragma unroll
  for (int mt = 0; mt < 4; mt++)
    #pragma unroll
    for (int ks = 0; ks < 2; ks++) {
      const float* wp = wfn + (mt * 16 + col) * 64 + ks * 32 + quad * 8;
      short8 v;
      #pragma unroll
      for (int j = 0; j < 8; j++) v[j] = f2bf(wp[j]);
      a[mt][ks] = v;
    }
  float cb[4][4];
  #pragma unroll
  for (int mt = 0; mt < 4; mt++)
    #pragma unroll
    for (int r = 0; r < 4; r++) cb[mt][r] = cf[n * 64 + mt * 16 + quad * 4 + r];
  const unsigned short* tn = t + (size_t)n * 64 * HWP;
  const float* xn = x + (size_t)n * 64 * HWP;
  float* x1n = x1 + (size_t)n * 64 * HWP;
  int pxbase = blockIdx.x * 512 + wid * 16 + col;
  for (int tile = 0; tile < 8; tile++) {
    int p = pxbase + tile * 64;
    short8 b[2];
    #pragma unroll
    for (int ks = 0; ks < 2; ks++)
      #pragma unroll
      for (int j = 0; j < 8; j++)
        b[ks][j] = (short)tn[(size_t)(ks * 32 + quad * 8 + j) * HWP + p];
    f32x4 acc[4];
    #pragma unroll
    for (int mt = 0; mt < 4; mt++) {
      acc[mt] = (f32x4){0.f, 0.f, 0.f, 0.f};
      acc[mt] = __builtin_amdgcn_mfma_f32_16x16x32_bf16(a[mt][0], b[0], acc[mt], 0, 0, 0);
      acc[mt] = __builtin_amdgcn_mfma_f32_16x16x32_bf16(a[mt][1], b[1], acc[mt], 0, 0, 0);
    }
    #pragma unroll
    for (int mt = 0; mt < 4; mt++)
      #pragma unroll
      for (int r = 0; r < 4; r++) {
        size_t idx = (size_t)(mt * 16 + quad * 4 + r) * HWP + p;
        x1n[idx] = xn[idx] + acc[mt][r] + cb[mt][r];
      }
  }
}

// -------- final via chained MFMA: out = x1 + b2*(W4 @ gate(W3' @ x1 + c3) + c4)
__global__ __launch_bounds__(256, 2) void final_mfma_kernel(
    const float* __restrict__ x1, const float* __restrict__ w3f,
    const float* __restrict__ c3f, const float* __restrict__ w4,
    const float* __restrict__ pb4, const float* __restrict__ beta2,
    float* __restrict__ out) {
  __shared__ float s_c3[128];
  __shared__ float s_b2[64];
  __shared__ float s_c4[64];
  __shared__ __align__(16) unsigned g_lds[64 * 33];  // [pixel][j/2], stride 33 dwords
  int n = blockIdx.y;
  int lane = threadIdx.x & 63, wid = threadIdx.x >> 6;
  int col = lane & 15, quad = lane >> 4;
  if (threadIdx.x < 128) s_c3[threadIdx.x] = c3f[n * 128 + threadIdx.x];
  if (threadIdx.x < 64) { s_b2[threadIdx.x] = beta2[threadIdx.x]; s_c4[threadIdx.x] = pb4[threadIdx.x]; }
  short8 a3[8][2];
  const float* wfn = w3f + (size_t)n * 128 * 64;
  #pragma unroll
  for (int mt = 0; mt < 8; mt++)
    #pragma unroll
    for (int ks = 0; ks < 2; ks++) {
      const float* wp = wfn + (mt * 16 + col) * 64 + ks * 32 + quad * 8;
      short8 v;
      #pragma unroll
      for (int j = 0; j < 8; j++) v[j] = f2bf(wp[j]);
      a3[mt][ks] = v;
    }
  short8 a4[4][2];
  #pragma unroll
  for (int mt = 0; mt < 4; mt++)
    #pragma unroll
    for (int ks = 0; ks < 2; ks++) {
      const float* wp = w4 + (mt * 16 + col) * 64 + ks * 32 + quad * 8;
      short8 v;
      #pragma unroll
      for (int j = 0; j < 8; j++) v[j] = f2bf(wp[j]);
      a4[mt][ks] = v;
    }
  __syncthreads();
  const float* x1n = x1 + (size_t)n * 64 * HWP;
  float* outn = out + (size_t)n * 64 * HWP;
  int pxbase = blockIdx.x * 512 + wid * 16 + col;
  unsigned* grow = g_lds + (wid * 16 + col) * 33;
  for (int tile = 0; tile < 8; tile++) {
    int p = pxbase + tile * 64;
    short8 b1[2];
    #pragma unroll
    for (int ks = 0; ks < 2; ks++)
      #pragma unroll
      for (int j = 0; j < 8; j++)
        b1[ks][j] = f2bf(x1n[(size_t)(ks * 32 + quad * 8 + j) * HWP + p]);
    f32x4 acc[8];
    #pragma unroll
    for (int mt = 0; mt < 8; mt++) {
      acc[mt] = (f32x4){0.f, 0.f, 0.f, 0.f};
      acc[mt] = __builtin_amdgcn_mfma_f32_16x16x32_bf16(a3[mt][0], b1[0], acc[mt], 0, 0, 0);
      acc[mt] = __builtin_amdgcn_mfma_f32_16x16x32_bf16(a3[mt][1], b1[1], acc[mt], 0, 0, 0);
    }
    #pragma unroll
    for (int mt = 0; mt < 4; mt++)
      #pragma unroll
      for (int rr = 0; rr < 2; rr++) {
        int j0 = mt * 16 + quad * 4 + rr * 2;
        float ga = (acc[mt][rr * 2]     + s_c3[j0])     * (acc[mt + 4][rr * 2]     + s_c3[64 + j0]);
        float gb = (acc[mt][rr * 2 + 1] + s_c3[j0 + 1]) * (acc[mt + 4][rr * 2 + 1] + s_c3[64 + j0 + 1]);
        unsigned lo = (unsigned short)f2bf(ga);
        unsigned hi = (unsigned short)f2bf(gb);
        grow[j0 >> 1] = lo | (hi << 16);
      }
    __syncthreads();
    short8 b2[2];
    #pragma unroll
    for (int ks = 0; ks < 2; ks++)
      #pragma unroll
      for (int w = 0; w < 4; w++) {
        unsigned u = grow[ks * 16 + quad * 4 + w];
        b2[ks][2 * w]     = (short)(u & 0xFFFFu);
        b2[ks][2 * w + 1] = (short)(u >> 16);
      }
    __syncthreads();
    f32x4 acc2[4];
    #pragma unroll
    for (int mt = 0; mt < 4; mt++) {
      acc2[mt] = (f32x4){0.f, 0.f, 0.f, 0.f};
      acc2[mt] = __builtin_amdgcn_mfma_f32_16x16x32_bf16(a4[mt][0], b2[0], acc2[mt], 0, 0, 0);
      acc2[mt] = __builtin_amdgcn_mfma_f32_16x16x32_bf16(a4[mt][1], b2[1], acc2[mt], 0, 0, 0);
    }
    #pragma unroll
    for (int mt = 0; mt < 4; mt++)
      #pragma unroll
      for (int r = 0; r < 4; r++) {
        int o = mt * 16 + quad * 4 + r;
        size_t idx = (size_t)o * HWP + p;
        outn[idx] = x1n[idx] + s_b2[o] * (acc2[mt][r] + s_c4[o]);
      }
  }
}

extern "C" void kernel_launch(void* const* d_in, const int* in_sizes, int n_in,
                              void* d_out, int out_size, void* d_ws, size_t ws_size,
                              hipStream_t stream) {
  const float* x    = (const float*)d_in[0];
  const float* ln1w = (const float*)d_in[1];
  const float* ln1b = (const float*)d_in[2];
  const float* pw1w = (const float*)d_in[3];
  const float* pw1b = (const float*)d_in[4];
  const float* dww  = (const float*)d_in[5];
  const float* dwb  = (const float*)d_in[6];
  const float* scaw = (const float*)d_in[7];
  const float* scab = (const float*)d_in[8];
  const float* pw2w = (const float*)d_in[9];
  const float* pw2b = (const float*)d_in[10];
  const float* ln2w = (const float*)d_in[11];
  const float* ln2b = (const float*)d_in[12];
  const float* pw3w = (const float*)d_in[13];
  const float* pw3b = (const float*)d_in[14];
  const float* pw4w = (const float*)d_in[15];
  const float* pw4b = (const float*)d_in[16];
  const float* beta1= (const float*)d_in[17];
  const float* beta2= (const float*)d_in[18];
  float* out = (float*)d_out;

  char* ws = (char*)d_ws;
  unsigned short* z  = (unsigned short*)ws;          // bf16 bits, 134 MB
  float*          x1 = (float*)ws;                    // reuses z region (z dead)
  unsigned short* t  = (unsigned short*)(ws + 134217728ull);  // bf16 bits, 67 MB
  float* sm = (float*)(ws + 134217728ull + 67108864ull);
  float* a1 = sm;            float* b1 = a1 + 512;
  float* w1f = b1 + 512;     float* c1f = w1f + 65536;
  float* pooled = c1f + 1024; float* sca = pooled + 512;
  float* w2f = sca + 512;    float* c2f = w2f + 32768;
  float* a2 = c2f + 512;     float* b2 = a2 + 512;
  float* w3f = b2 + 512;     float* c3f = w3f + 65536;

  hipLaunchKernelGGL(ln_stats_kernel, dim3(512), dim3(256), 0, stream, x, ln1w, ln1b, a1, b1);
  hipLaunchKernelGGL(fold_kernel, dim3(4), dim3(256), 0, stream, pw1w, pw1b, a1, b1, w1f, c1f, 128);
  hipLaunchKernelGGL(gemm_pw1_kernel, dim3(128, 8), dim3(256), 0, stream, x, w1f, c1f, z);
  hipLaunchKernelGGL(dwgate_kernel, dim3(512), dim3(256), 0, stream, z, dww, dwb, t, pooled);
  hipLaunchKernelGGL(sca_kernel, dim3(2), dim3(256), 0, stream, pooled, scaw, scab, sca);
  hipLaunchKernelGGL(fold_pw2_kernel, dim3(2), dim3(256), 0, stream, pw2w, pw2b, sca, beta1, w2f, c2f);
  hipLaunchKernelGGL(gemm_pw2_kernel, dim3(128, 8), dim3(256), 0, stream, t, x, w2f, c2f, x1);
  hipLaunchKernelGGL(ln_stats_kernel, dim3(512), dim3(256), 0, stream, x1, ln2w, ln2b, a2, b2);
  hipLaunchKernelGGL(fold_kernel, dim3(4), dim3(256), 0, stream, pw3w, pw3b, a2, b2, w3f, c3f, 128);
  hipLaunchKernelGGL(final_mfma_kernel, dim3(128, 8), dim3(256), 0, stream,
                     x1, w3f, c3f, pw4w, pw4b, beta2, out);
}